// Round 5
// baseline (806.714 us; speedup 1.0000x reference)
//
#include <hip/hip_runtime.h>
#include <math.h>

// Problem constants
static constexpr int B  = 2;
static constexpr int S  = 512;
static constexpr int D  = 256;
static constexpr int N  = 16;
static constexpr int DI = 512;
static constexpr int CHUNK = 32;
static constexpr int NCHUNK = S / CHUNK;   // 16
static constexpr int DN = DI * N;          // 8192
static constexpr int NSLOT = 16;           // slots 0..14 = past chunk ks, slot 15 = new chunk

typedef unsigned int uint32;
typedef unsigned short ushort16;
using bf16x8 = __attribute__((ext_vector_type(8))) short;
using f32x4  = __attribute__((ext_vector_type(4))) float;

__device__ __forceinline__ ushort16 f2bf(float f) {
    uint32 u = __float_as_uint(f);
    u = (u + 0x7fffu + ((u >> 16) & 1u)) >> 16;   // RNE
    return (ushort16)u;
}
__device__ __forceinline__ float bflo(uint32 u) { return __uint_as_float(u << 16); }
__device__ __forceinline__ float bfhi(uint32 u) { return __uint_as_float(u & 0xffff0000u); }
__device__ __forceinline__ uint32 pk2(float a, float b) {
    return (uint32)(ushort16)f2bf(a) | ((uint32)(ushort16)f2bf(b) << 16);
}

// ---------------- LayerNorm: one wave per row, bf16 output ----------------
__global__ void ln_k(const float* __restrict__ x, const float* __restrict__ w,
                     const float* __restrict__ bias, ushort16* __restrict__ xnb) {
    int row = blockIdx.x;
    int lane = threadIdx.x;
    float4 v = *(const float4*)(x + row * D + lane * 4);
    float s = v.x + v.y + v.z + v.w;
    float q = v.x * v.x + v.y * v.y + v.z * v.z + v.w * v.w;
    for (int m = 1; m < 64; m <<= 1) { s += __shfl_xor(s, m); q += __shfl_xor(q, m); }
    float mu  = s * (1.0f / D);
    float var = q * (1.0f / D) - mu * mu;
    float rs  = rsqrtf(var + 1e-5f);
    float4 wv = *(const float4*)(w + lane * 4);
    float4 bv = *(const float4*)(bias + lane * 4);
    float4 o;
    o.x = (v.x - mu) * rs * wv.x + bv.x;
    o.y = (v.y - mu) * rs * wv.y + bv.y;
    o.z = (v.z - mu) * rs * wv.z + bv.z;
    o.w = (v.w - mu) * rs * wv.w + bv.w;
    uint2 pk;
    pk.x = pk2(o.x, o.y);
    pk.y = pk2(o.z, o.w);
    *(uint2*)(xnb + row * D + lane * 4) = pk;
}

// ---------------- generic f32 -> bf16 cast ----------------
__global__ void wcast_k(const float* __restrict__ src, ushort16* __restrict__ dst) {
    int i = blockIdx.x * 256 + threadIdx.x;
    float4 v = *(const float4*)(src + (size_t)i * 4);
    uint2 pk;
    pk.x = pk2(v.x, v.y);
    pk.y = pk2(v.z, v.w);
    *(uint2*)(dst + (size_t)i * 4) = pk;
}

// ---------------- bf16 MFMA GEMM: C[M,Nc] = A[M,K] @ W[Nc,K]^T (+res, f32 out) -------
// 64x64 tile, 4 waves = 2x2 quadrants of 32x32, each 2x2 of 16x16x32 frags.
__global__ __launch_bounds__(256) void gemmb_k(const ushort16* __restrict__ A,
                                               const ushort16* __restrict__ W,
                                               const float* __restrict__ res,
                                               float* __restrict__ C,
                                               int M, int Nc, int K) {
    __shared__ __align__(16) short As[64 * 40];
    __shared__ __align__(16) short Ws[64 * 40];
    int tid = threadIdx.x;
    int l = tid & 63, wid = tid >> 6;
    int wm = wid & 1, wn = wid >> 1;
    int row0 = blockIdx.y * 64, col0 = blockIdx.x * 64;
    int r = tid >> 2, kseg = (tid & 3) * 8;
    f32x4 acc[2][2] = {};
    for (int k0 = 0; k0 < K; k0 += 32) {
        *(uint4*)&As[r * 40 + kseg] = *(const uint4*)(A + (size_t)(row0 + r) * K + k0 + kseg);
        *(uint4*)&Ws[r * 40 + kseg] = *(const uint4*)(W + (size_t)(col0 + r) * K + k0 + kseg);
        __syncthreads();
        bf16x8 aF[2], bF[2];
        #pragma unroll
        for (int am = 0; am < 2; ++am)
            aF[am] = *(const bf16x8*)&As[(wm * 32 + am * 16 + (l & 15)) * 40 + (l >> 4) * 8];
        #pragma unroll
        for (int bn = 0; bn < 2; ++bn)
            bF[bn] = *(const bf16x8*)&Ws[(wn * 32 + bn * 16 + (l & 15)) * 40 + (l >> 4) * 8];
        #pragma unroll
        for (int am = 0; am < 2; ++am)
            #pragma unroll
            for (int bn = 0; bn < 2; ++bn)
                acc[am][bn] = __builtin_amdgcn_mfma_f32_16x16x32_bf16(aF[am], bF[bn], acc[am][bn], 0, 0, 0);
        __syncthreads();
    }
    #pragma unroll
    for (int am = 0; am < 2; ++am)
        #pragma unroll
        for (int bn = 0; bn < 2; ++bn) {
            int cc = col0 + wn * 32 + bn * 16 + (l & 15);
            #pragma unroll
            for (int reg = 0; reg < 4; ++reg) {
                int rr = row0 + wm * 32 + am * 16 + (l >> 4) * 4 + reg;
                float v = acc[am][bn][reg];
                if (res) v += res[(size_t)rr * Nc + cc];
                C[(size_t)rr * Nc + cc] = v;
            }
        }
}

// ---------------- cast xz[:, :DI] -> xpb (bf16, with 3-row zero halo per batch) -------
__global__ void cast_k(const float* __restrict__ xz, ushort16* __restrict__ xpb) {
    int i = blockIdx.x * 256 + threadIdx.x;
    int row = i >> 6;
    int off = (i & 63) * 8;
    int b = row >> 9, t = row & (S - 1);
    float4 v0 = *(const float4*)(xz + (size_t)row * (2 * DI) + off);
    float4 v1 = *(const float4*)(xz + (size_t)row * (2 * DI) + off + 4);
    uint4 pk;
    pk.x = pk2(v0.x, v0.y);
    pk.y = pk2(v0.z, v0.w);
    pk.z = pk2(v1.x, v1.y);
    pk.w = pk2(v1.z, v1.w);
    *(uint4*)(xpb + ((size_t)(b * (S + 3) + 3 + t)) * DI + off) = pk;
}

// ---------------- Causal conv via bf16 MFMA + bias + silu ----------------
__global__ __launch_bounds__(256) void convm_k(const ushort16* __restrict__ xpb,
                                               const float* __restrict__ conv_w,
                                               const float* __restrict__ conv_b,
                                               float* __restrict__ x_act) {
    __shared__ __align__(16) short AxS[35 * 40];
    __shared__ __align__(16) short WbS[4 * 32 * 40];
    int tid = threadIdx.x;
    int l = tid & 63, wid = tid >> 6;
    int wm = wid & 1, wn = wid >> 1;
    int o0 = blockIdx.x * 32;
    int mt = blockIdx.y;
    int b = mt >> 4, tl0 = (mt & 15) * 32;
    f32x4 acc = {0.f, 0.f, 0.f, 0.f};

    for (int k0 = 0; k0 < DI; k0 += 32) {
        if (tid < 140) {
            int rr = tid >> 2, seg = tid & 3;
            uint4 v = *(const uint4*)(xpb + ((size_t)(b * (S + 3) + tl0 + rr)) * DI + k0 + seg * 8);
            *(uint4*)&AxS[rr * 40 + seg * 8] = v;
        }
        #pragma unroll
        for (int it = 0; it < 4; ++it) {
            int p = it * 256 + tid;
            int o = p >> 5, i = p & 31;
            float4 w4 = *(const float4*)(conv_w + ((size_t)(o0 + o) * DI + (k0 + i)) * 4);
            WbS[(0 * 32 + o) * 40 + i] = (short)f2bf(w4.x);
            WbS[(1 * 32 + o) * 40 + i] = (short)f2bf(w4.y);
            WbS[(2 * 32 + o) * 40 + i] = (short)f2bf(w4.z);
            WbS[(3 * 32 + o) * 40 + i] = (short)f2bf(w4.w);
        }
        __syncthreads();
        #pragma unroll
        for (int k = 0; k < 4; ++k) {
            bf16x8 aF = *(const bf16x8*)&AxS[(wm * 16 + (l & 15) + k) * 40 + (l >> 4) * 8];
            bf16x8 bF = *(const bf16x8*)&WbS[(k * 32 + wn * 16 + (l & 15)) * 40 + (l >> 4) * 8];
            acc = __builtin_amdgcn_mfma_f32_16x16x32_bf16(aF, bF, acc, 0, 0, 0);
        }
        __syncthreads();
    }
    int oc = o0 + wn * 16 + (l & 15);
    float bia = conv_b[oc];
    #pragma unroll
    for (int reg = 0; reg < 4; ++reg) {
        int m = wm * 16 + (l >> 4) * 4 + reg;
        float v = acc[reg] + bia;
        x_act[((size_t)(b * S + tl0 + m)) * DI + oc] = v / (1.0f + expf(-v));
    }
}

// ---------------- ssm = x_act @ W_xp^T (33 outputs) ----------------
__global__ void ssm_k(const float* __restrict__ x_act, const float* __restrict__ W_xp,
                      float* __restrict__ dt_raw, float* __restrict__ Bm, float* __restrict__ Cm) {
    int row = blockIdx.x * 4 + (threadIdx.x >> 6);
    int lane = threadIdx.x & 63;
    const float* xr = x_act + (size_t)row * DI + lane * 8;
    float4 v0 = *(const float4*)xr;
    float4 v1 = *(const float4*)(xr + 4);
    for (int j = 0; j < 2 * N + 1; ++j) {
        const float* wr = W_xp + (size_t)j * DI + lane * 8;
        float4 w0 = *(const float4*)wr;
        float4 w1 = *(const float4*)(wr + 4);
        float acc = v0.x * w0.x + v0.y * w0.y + v0.z * w0.z + v0.w * w0.w
                  + v1.x * w1.x + v1.y * w1.y + v1.z * w1.z + v1.w * w1.w;
        for (int m = 1; m < 64; m <<= 1) acc += __shfl_xor(acc, m);
        if (lane == 0) {
            if (j == 0)           dt_raw[row] = acc;
            else if (j < 1 + N)   Bm[(size_t)row * N + (j - 1)] = acc;
            else                  Cm[(size_t)row * N + (j - 1 - N)] = acc;
        }
    }
}

// ---------------- rdeg = 1/max(sum_{s<t} adj,1); flag[t] ----------------
__global__ void deg_k(const float* __restrict__ adj, float* __restrict__ rdeg, int* __restrict__ flagI) {
    int t = blockIdx.x & (S - 1), b = blockIdx.x >> 9;
    int lane = threadIdx.x;
    const float* row = adj + ((size_t)(b * S + t)) * S;
    float s = 0.0f; bool anyp = false;
    for (int i = lane; i < t; i += 64) { float v = row[i]; s += v; anyp |= (v > 0.0f); }
    for (int m = 1; m < 64; m <<= 1) s += __shfl_xor(s, m);
    bool any = __any(anyp);
    if (lane == 0) {
        rdeg[b * S + t] = 1.0f / fmaxf(s, 1.0f);
        if (t > 0 && any) atomicOr(flagI + t, 1);
    }
}

// ---------------- E = exp(-softplus(dt)), zs = silu(z) ----------------
__global__ void ez_k(const float* __restrict__ dt_raw, const float* __restrict__ W_dt,
                     const float* __restrict__ b_dt, const float* __restrict__ xz,
                     float* __restrict__ E, float* __restrict__ zs) {
    int i = blockIdx.x * 256 + threadIdx.x;
    int d = i & (DI - 1);
    int row = i >> 9;
    float vv = dt_raw[row] * W_dt[d] + b_dt[d];
    E[i] = 1.0f / (1.0f + expf(vv));
    float z = xz[(size_t)row * (2 * DI) + DI + d];
    zs[i] = z / (1.0f + expf(-z));
}

// ================= fused chunk kernel (64-thread blocks) =================
// Gpart layout: [parity][slot][b][dn][j32] bf16. slot ks<15 = contribution of
// past chunk ks, slot 15 = previous chunk (from scan registers).
// blocks [0,256): scan role, 1 wave = 4 d-groups x 16 n.
// blocks [256,2176): gpast role: (ks,b,tile), chunk ks -> chunk c+1, 128 dn per block.
__global__ __launch_bounds__(64) void chunk_k(const float* __restrict__ adj,
                                              const float* __restrict__ x_act,
                                              const float* __restrict__ E,
                                              const float* __restrict__ Bm,
                                              const float* __restrict__ Cm,
                                              const float* __restrict__ rdeg,
                                              const int* __restrict__ flagI,
                                              const float* __restrict__ Wr,
                                              const float* __restrict__ br,
                                              ushort16* __restrict__ Gpartb,
                                              ushort16* __restrict__ histb,
                                              float* __restrict__ hlast,
                                              const float* __restrict__ zs,
                                              ushort16* __restrict__ yzb, int c) {
    int tid = threadIdx.x;
    int cb = c * CHUNK;
    const size_t PSTR = (size_t)NSLOT * B * DN * 32;   // ushorts per parity

    if (blockIdx.x < 256) {
        // ---------------- scan role ----------------
        __shared__ float eL[CHUNK * 4];
        __shared__ float xaL[CHUNK * 4];
        __shared__ float BnL[CHUNK * 16];
        __shared__ float CnL[CHUNK * 16];
        __shared__ float rdegL[CHUNK];
        __shared__ int   flL[CHUNK];

        int b = blockIdx.x >> 7;
        int d0 = (blockIdx.x & 127) << 2;
        int n = tid & 15, grp = tid >> 4;
        int d = d0 + grp;
        int dn = d * N + n;

        // stage small per-chunk operands (coalesced bursts, off the serial chain)
        {
            int j = tid >> 1, half = tid & 1;
            float2 ev = *(const float2*)(E     + ((size_t)(b * S + cb + j)) * DI + d0 + half * 2);
            float2 xv = *(const float2*)(x_act + ((size_t)(b * S + cb + j)) * DI + d0 + half * 2);
            eL [j * 4 + half * 2]     = ev.x;
            eL [j * 4 + half * 2 + 1] = ev.y;
            xaL[j * 4 + half * 2]     = xv.x;
            xaL[j * 4 + half * 2 + 1] = xv.y;
            int nn = tid & 15;
            #pragma unroll
            for (int p = 0; p < 8; ++p) {
                int jj = (tid >> 4) + p * 4;
                BnL[jj * 16 + nn] = Bm[((size_t)(b * S + cb + jj)) * N + nn];
                CnL[jj * 16 + nn] = Cm[((size_t)(b * S + cb + jj)) * N + nn];
            }
            if (tid < 32) {
                rdegL[tid] = rdeg[b * S + cb + tid];
                flL[tid]   = flagI[cb + tid];
            }
        }

        // pre-sum all 16 Gpart slots into registers (coalesced 64B bursts)
        float gsum[CHUNK];
        #pragma unroll
        for (int j = 0; j < CHUNK; ++j) gsum[j] = 0.0f;
        {
            const ushort16* gb = Gpartb + (size_t)(c & 1) * PSTR;
            #pragma unroll
            for (int sl = 0; sl < NSLOT; ++sl) {
                const ushort16* p = gb + (((size_t)sl * B + b) * DN + dn) * 32;
                #pragma unroll
                for (int qi = 0; qi < 4; ++qi) {
                    uint4 q = *(const uint4*)(p + qi * 8);
                    gsum[qi * 8 + 0] += bflo(q.x); gsum[qi * 8 + 1] += bfhi(q.x);
                    gsum[qi * 8 + 2] += bflo(q.y); gsum[qi * 8 + 3] += bfhi(q.y);
                    gsum[qi * 8 + 4] += bflo(q.z); gsum[qi * 8 + 5] += bfhi(q.z);
                    gsum[qi * 8 + 6] += bflo(q.w); gsum[qi * 8 + 7] += bfhi(q.w);
                }
            }
        }

        float wr[16];
        #pragma unroll
        for (int m = 0; m < 16; ++m) wr[m] = Wr[n * 16 + m];
        float brn = br[n];
        float h = (c == 0) ? 0.0f : hlast[b * DN + dn];

        const float* adjbase = adj + (size_t)(b * S + cb) * S + cb;  // row j: +j*S (uniform)
        float hreg[CHUNK];

        #pragma unroll
        for (int j = 0; j < CHUNK; ++j) {
            float e  = eL [j * 4 + grp];
            float xa = xaL[j * 4 + grp];
            float Bn = BnL[j * 16 + n];
            h = h * e + xa * Bn;

            float g0 = gsum[j], g1 = 0.0f, g2 = 0.0f, g3 = 0.0f;
            const float* ar = adjbase + (size_t)j * S;
            #pragma unroll
            for (int sp = 0; sp < j; ++sp) {
                float a = ar[sp];              // block-uniform scalar load
                if ((sp & 3) == 0) g0 += a * hreg[sp];
                else if ((sp & 3) == 1) g1 += a * hreg[sp];
                else if ((sp & 3) == 2) g2 += a * hreg[sp];
                else g3 += a * hreg[sp];
            }
            float g = ((g0 + g1) + (g2 + g3)) * rdegL[j];

            float a0 = brn, a1 = 0.0f;
            #pragma unroll
            for (int m = 0; m < 16; m += 2) {
                a0 += __shfl(g, m, 16)     * wr[m];
                a1 += __shfl(g, m + 1, 16) * wr[m + 1];
            }
            float acc = a0 + a1;
            if (flL[j]) h += 0.1f * acc / (1.0f + expf(-acc));
            hreg[j] = h;
        }
        hlast[b * DN + dn] = h;

        // tail: hist stores + y outputs
        size_t baseTD = ((size_t)(b * S + cb)) * DI + d;
        size_t baseDN = ((size_t)cb * B + b) * DN + dn;
        #pragma unroll
        for (int j = 0; j < CHUNK; ++j)
            histb[baseDN + (size_t)j * (B * DN)] = f2bf(hreg[j]);
        #pragma unroll
        for (int j = 0; j < CHUNK; ++j) {
            float rs = hreg[j] * CnL[j * 16 + n];
            rs += __shfl_xor(rs, 1);
            rs += __shfl_xor(rs, 2);
            rs += __shfl_xor(rs, 4);
            rs += __shfl_xor(rs, 8);
            if (n == 0) {
                float zv = zs[baseTD + (size_t)j * DI];
                yzb[baseTD + (size_t)j * DI] = f2bf(rs * zv);
            }
        }

        // G_new for chunk c+1 (slot 15) from register history
        if (c < NCHUNK - 1) {
            const float* adjN = adj + (size_t)(b * S + cb + CHUNK) * S + cb;
            float gn[CHUNK];
            #pragma unroll
            for (int jj = 0; jj < CHUNK; ++jj) {
                float a0 = 0.0f, a1 = 0.0f;
                const float* arN = adjN + (size_t)jj * S;
                #pragma unroll
                for (int sp = 0; sp < CHUNK; sp += 2) {
                    a0 += arN[sp]     * hreg[sp];
                    a1 += arN[sp + 1] * hreg[sp + 1];
                }
                gn[jj] = a0 + a1;
            }
            ushort16* gw = Gpartb + (size_t)((c + 1) & 1) * PSTR
                         + (((size_t)15 * B + b) * DN + dn) * 32;
            #pragma unroll
            for (int qi = 0; qi < 4; ++qi) {
                uint4 q;
                q.x = pk2(gn[qi * 8 + 0], gn[qi * 8 + 1]);
                q.y = pk2(gn[qi * 8 + 2], gn[qi * 8 + 3]);
                q.z = pk2(gn[qi * 8 + 4], gn[qi * 8 + 5]);
                q.w = pk2(gn[qi * 8 + 6], gn[qi * 8 + 7]);
                *(uint4*)(gw + qi * 8) = q;
            }
        }
    } else {
        // ---------------- gpast role: chunk ks -> chunk c+1 ----------------
        if (c == 0 || c >= NCHUNK - 1) return;
        int idx = blockIdx.x - 256;
        int tile = idx & 63;               // 64 tiles x 128 dn
        int b = (idx >> 6) & 1;
        int ks = idx >> 7;                 // 0..14
        if (ks >= c) return;
        int s0 = ks * CHUNK;
        int dn0 = tile * 128 + tid * 2;

        float accA[CHUNK], accB[CHUNK];
        #pragma unroll
        for (int j = 0; j < CHUNK; ++j) { accA[j] = 0.0f; accB[j] = 0.0f; }

        const float* adjbase = adj + (size_t)(b * S + cb + CHUNK) * S + s0;  // row j: +j*S
        for (int sq = 0; sq < 8; ++sq) {
            float h0[4], h1[4];
            #pragma unroll
            for (int ss = 0; ss < 4; ++ss) {
                uint32 u = *(const uint32*)(histb + ((size_t)(s0 + sq * 4 + ss) * B + b) * DN + dn0);
                h0[ss] = bflo(u);
                h1[ss] = bfhi(u);
            }
            #pragma unroll
            for (int j = 0; j < CHUNK; ++j) {
                float4 a = *(const float4*)(adjbase + (size_t)j * S + sq * 4);  // uniform
                accA[j] += a.x * h0[0]; accB[j] += a.x * h1[0];
                accA[j] += a.y * h0[1]; accB[j] += a.y * h1[1];
                accA[j] += a.z * h0[2]; accB[j] += a.z * h1[2];
                accA[j] += a.w * h0[3]; accB[j] += a.w * h1[3];
            }
        }
        ushort16* gw = Gpartb + (size_t)((c + 1) & 1) * PSTR
                     + (((size_t)ks * B + b) * DN + dn0) * 32;
        #pragma unroll
        for (int qi = 0; qi < 4; ++qi) {
            uint4 qa, qb;
            qa.x = pk2(accA[qi * 8 + 0], accA[qi * 8 + 1]);
            qa.y = pk2(accA[qi * 8 + 2], accA[qi * 8 + 3]);
            qa.z = pk2(accA[qi * 8 + 4], accA[qi * 8 + 5]);
            qa.w = pk2(accA[qi * 8 + 6], accA[qi * 8 + 7]);
            qb.x = pk2(accB[qi * 8 + 0], accB[qi * 8 + 1]);
            qb.y = pk2(accB[qi * 8 + 2], accB[qi * 8 + 3]);
            qb.z = pk2(accB[qi * 8 + 4], accB[qi * 8 + 5]);
            qb.w = pk2(accB[qi * 8 + 6], accB[qi * 8 + 7]);
            *(uint4*)(gw + qi * 8) = qa;
            *(uint4*)(gw + 32 + qi * 8) = qb;
        }
    }
}

// ---------------- launch ----------------
extern "C" void kernel_launch(void* const* d_in, const int* in_sizes, int n_in,
                              void* d_out, int out_size, void* d_ws, size_t ws_size,
                              hipStream_t stream) {
    const float* x      = (const float*)d_in[0];
    const float* adj    = (const float*)d_in[1];
    const float* ln_w   = (const float*)d_in[2];
    const float* ln_b   = (const float*)d_in[3];
    const float* W_in   = (const float*)d_in[4];
    const float* conv_w = (const float*)d_in[5];
    const float* conv_b = (const float*)d_in[6];
    const float* W_xp   = (const float*)d_in[7];
    const float* W_dt   = (const float*)d_in[8];
    const float* b_dt   = (const float*)d_in[9];
    const float* Wr     = (const float*)d_in[10];
    const float* br     = (const float*)d_in[11];
    const float* W_out  = (const float*)d_in[12];
    float* out = (float*)d_out;

    float* ws = (float*)d_ws;
    size_t off = 0;
    float* xz     = ws + off; off += (size_t)B * S * 2 * DI;
    float* x_act  = ws + off; off += (size_t)B * S * DI;
    float* dt_raw = ws + off; off += (size_t)B * S;
    float* Bmb    = ws + off; off += (size_t)B * S * N;
    float* Cmb    = ws + off; off += (size_t)B * S * N;
    float* rdegp  = ws + off; off += (size_t)B * S;
    int*   flagI  = (int*)(ws + off); off += S;
    float* Ebuf   = ws + off; off += (size_t)B * S * DI;
    float* zsbuf  = ws + off; off += (size_t)B * S * DI;
    float* hlast  = ws + off; off += (size_t)B * DN;
    ushort16* xnb    = (ushort16*)(ws + off); off += (size_t)B * S * D / 2;
    ushort16* yzb    = (ushort16*)(ws + off); off += (size_t)B * S * DI / 2;
    ushort16* histb  = (ushort16*)(ws + off); off += (size_t)S * B * DN / 2;
    ushort16* Gpartb = (ushort16*)(ws + off); off += (size_t)2 * NSLOT * B * DN * 32 / 2;
    ushort16* xpb    = (ushort16*)(ws + off); off += (size_t)B * (S + 3) * DI / 2;
    ushort16* W_inb  = (ushort16*)(ws + off); off += (size_t)2 * DI * D / 2;
    ushort16* W_outb = (ushort16*)(ws + off); off += (size_t)D * DI / 2;

    hipMemsetAsync(flagI, 0, S * sizeof(int), stream);
    hipMemsetAsync(Gpartb, 0, (size_t)2 * NSLOT * B * DN * 32 * 2, stream);
    hipMemsetAsync(xpb, 0, (size_t)B * (S + 3) * DI * 2, stream);

    ln_k<<<B * S, 64, 0, stream>>>(x, ln_w, ln_b, xnb);
    wcast_k<<<(2 * DI * D) / 1024, 256, 0, stream>>>(W_in, W_inb);
    wcast_k<<<(D * DI) / 1024, 256, 0, stream>>>(W_out, W_outb);
    gemmb_k<<<dim3(2 * DI / 64, B * S / 64), 256, 0, stream>>>(xnb, W_inb, nullptr, xz, B * S, 2 * DI, D);
    cast_k<<<B * S * DI / (256 * 8), 256, 0, stream>>>(xz, xpb);
    convm_k<<<dim3(DI / 32, B * S / 32), 256, 0, stream>>>(xpb, conv_w, conv_b, x_act);
    ssm_k<<<B * S / 4, 256, 0, stream>>>(x_act, W_xp, dt_raw, Bmb, Cmb);
    deg_k<<<B * S, 64, 0, stream>>>(adj, rdegp, flagI);
    ez_k<<<B * S * DI / 256, 256, 0, stream>>>(dt_raw, W_dt, b_dt, xz, Ebuf, zsbuf);

    for (int c = 0; c < NCHUNK; ++c)
        chunk_k<<<256 + 15 * B * 64, 64, 0, stream>>>(adj, x_act, Ebuf, Bmb, Cmb, rdegp, flagI,
                                                      Wr, br, Gpartb, histb, hlast, zsbuf, yzb, c);

    gemmb_k<<<dim3(D / 64, B * S / 64), 256, 0, stream>>>(yzb, W_outb, x, out, B * S, D, DI);
}

// Round 6
// 599.066 us; speedup vs baseline: 1.3466x; 1.3466x over previous
//
#include <hip/hip_runtime.h>
#include <math.h>

// Problem constants
static constexpr int B  = 2;
static constexpr int S  = 512;
static constexpr int D  = 256;
static constexpr int N  = 16;
static constexpr int DI = 512;
static constexpr int CHUNK = 32;
static constexpr int NCHUNK = S / CHUNK;   // 16
static constexpr int DN = DI * N;          // 8192

typedef unsigned int uint32;
typedef unsigned short ushort16;
using bf16x8 = __attribute__((ext_vector_type(8))) short;
using f32x4  = __attribute__((ext_vector_type(4))) float;

__device__ __forceinline__ ushort16 f2bf(float f) {
    uint32 u = __float_as_uint(f);
    u = (u + 0x7fffu + ((u >> 16) & 1u)) >> 16;   // RNE
    return (ushort16)u;
}
__device__ __forceinline__ float bflo(uint32 u) { return __uint_as_float(u << 16); }
__device__ __forceinline__ float bfhi(uint32 u) { return __uint_as_float(u & 0xffff0000u); }
__device__ __forceinline__ uint32 pk2(float a, float b) {
    return (uint32)(ushort16)f2bf(a) | ((uint32)(ushort16)f2bf(b) << 16);
}

// ---------------- LayerNorm: one wave per row, bf16 output ----------------
__global__ void ln_k(const float* __restrict__ x, const float* __restrict__ w,
                     const float* __restrict__ bias, ushort16* __restrict__ xnb) {
    int row = blockIdx.x;
    int lane = threadIdx.x;
    float4 v = *(const float4*)(x + row * D + lane * 4);
    float s = v.x + v.y + v.z + v.w;
    float q = v.x * v.x + v.y * v.y + v.z * v.z + v.w * v.w;
    for (int m = 1; m < 64; m <<= 1) { s += __shfl_xor(s, m); q += __shfl_xor(q, m); }
    float mu  = s * (1.0f / D);
    float var = q * (1.0f / D) - mu * mu;
    float rs  = rsqrtf(var + 1e-5f);
    float4 wv = *(const float4*)(w + lane * 4);
    float4 bv = *(const float4*)(bias + lane * 4);
    float4 o;
    o.x = (v.x - mu) * rs * wv.x + bv.x;
    o.y = (v.y - mu) * rs * wv.y + bv.y;
    o.z = (v.z - mu) * rs * wv.z + bv.z;
    o.w = (v.w - mu) * rs * wv.w + bv.w;
    uint2 pk;
    pk.x = pk2(o.x, o.y);
    pk.y = pk2(o.z, o.w);
    *(uint2*)(xnb + row * D + lane * 4) = pk;
}

// ---------------- generic f32 -> bf16 cast ----------------
__global__ void wcast_k(const float* __restrict__ src, ushort16* __restrict__ dst) {
    int i = blockIdx.x * 256 + threadIdx.x;
    float4 v = *(const float4*)(src + (size_t)i * 4);
    uint2 pk;
    pk.x = pk2(v.x, v.y);
    pk.y = pk2(v.z, v.w);
    *(uint2*)(dst + (size_t)i * 4) = pk;
}

// ---------------- bf16 MFMA GEMM: C[M,Nc] = A[M,K] @ W[Nc,K]^T (+res, f32 out) -------
__global__ __launch_bounds__(256) void gemmb_k(const ushort16* __restrict__ A,
                                               const ushort16* __restrict__ W,
                                               const float* __restrict__ res,
                                               float* __restrict__ C,
                                               int M, int Nc, int K) {
    __shared__ __align__(16) short As[64 * 40];
    __shared__ __align__(16) short Ws[64 * 40];
    int tid = threadIdx.x;
    int l = tid & 63, wid = tid >> 6;
    int wm = wid & 1, wn = wid >> 1;
    int row0 = blockIdx.y * 64, col0 = blockIdx.x * 64;
    int r = tid >> 2, kseg = (tid & 3) * 8;
    f32x4 acc[2][2] = {};
    for (int k0 = 0; k0 < K; k0 += 32) {
        *(uint4*)&As[r * 40 + kseg] = *(const uint4*)(A + (size_t)(row0 + r) * K + k0 + kseg);
        *(uint4*)&Ws[r * 40 + kseg] = *(const uint4*)(W + (size_t)(col0 + r) * K + k0 + kseg);
        __syncthreads();
        bf16x8 aF[2], bF[2];
        #pragma unroll
        for (int am = 0; am < 2; ++am)
            aF[am] = *(const bf16x8*)&As[(wm * 32 + am * 16 + (l & 15)) * 40 + (l >> 4) * 8];
        #pragma unroll
        for (int bn = 0; bn < 2; ++bn)
            bF[bn] = *(const bf16x8*)&Ws[(wn * 32 + bn * 16 + (l & 15)) * 40 + (l >> 4) * 8];
        #pragma unroll
        for (int am = 0; am < 2; ++am)
            #pragma unroll
            for (int bn = 0; bn < 2; ++bn)
                acc[am][bn] = __builtin_amdgcn_mfma_f32_16x16x32_bf16(aF[am], bF[bn], acc[am][bn], 0, 0, 0);
        __syncthreads();
    }
    #pragma unroll
    for (int am = 0; am < 2; ++am)
        #pragma unroll
        for (int bn = 0; bn < 2; ++bn) {
            int cc = col0 + wn * 32 + bn * 16 + (l & 15);
            #pragma unroll
            for (int reg = 0; reg < 4; ++reg) {
                int rr = row0 + wm * 32 + am * 16 + (l >> 4) * 4 + reg;
                float v = acc[am][bn][reg];
                if (res) v += res[(size_t)rr * Nc + cc];
                C[(size_t)rr * Nc + cc] = v;
            }
        }
}

// ---------------- cast xz[:, :DI] -> xpb (bf16, with 3-row zero halo per batch) -------
__global__ void cast_k(const float* __restrict__ xz, ushort16* __restrict__ xpb) {
    int i = blockIdx.x * 256 + threadIdx.x;
    int row = i >> 6;
    int off = (i & 63) * 8;
    int b = row >> 9, t = row & (S - 1);
    float4 v0 = *(const float4*)(xz + (size_t)row * (2 * DI) + off);
    float4 v1 = *(const float4*)(xz + (size_t)row * (2 * DI) + off + 4);
    uint4 pk;
    pk.x = pk2(v0.x, v0.y);
    pk.y = pk2(v0.z, v0.w);
    pk.z = pk2(v1.x, v1.y);
    pk.w = pk2(v1.z, v1.w);
    *(uint4*)(xpb + ((size_t)(b * (S + 3) + 3 + t)) * DI + off) = pk;
}

// ---------------- Causal conv via bf16 MFMA + bias + silu ----------------
__global__ __launch_bounds__(256) void convm_k(const ushort16* __restrict__ xpb,
                                               const float* __restrict__ conv_w,
                                               const float* __restrict__ conv_b,
                                               float* __restrict__ x_act) {
    __shared__ __align__(16) short AxS[35 * 40];
    __shared__ __align__(16) short WbS[4 * 32 * 40];
    int tid = threadIdx.x;
    int l = tid & 63, wid = tid >> 6;
    int wm = wid & 1, wn = wid >> 1;
    int o0 = blockIdx.x * 32;
    int mt = blockIdx.y;
    int b = mt >> 4, tl0 = (mt & 15) * 32;
    f32x4 acc = {0.f, 0.f, 0.f, 0.f};

    for (int k0 = 0; k0 < DI; k0 += 32) {
        if (tid < 140) {
            int rr = tid >> 2, seg = tid & 3;
            uint4 v = *(const uint4*)(xpb + ((size_t)(b * (S + 3) + tl0 + rr)) * DI + k0 + seg * 8);
            *(uint4*)&AxS[rr * 40 + seg * 8] = v;
        }
        #pragma unroll
        for (int it = 0; it < 4; ++it) {
            int p = it * 256 + tid;
            int o = p >> 5, i = p & 31;
            float4 w4 = *(const float4*)(conv_w + ((size_t)(o0 + o) * DI + (k0 + i)) * 4);
            WbS[(0 * 32 + o) * 40 + i] = (short)f2bf(w4.x);
            WbS[(1 * 32 + o) * 40 + i] = (short)f2bf(w4.y);
            WbS[(2 * 32 + o) * 40 + i] = (short)f2bf(w4.z);
            WbS[(3 * 32 + o) * 40 + i] = (short)f2bf(w4.w);
        }
        __syncthreads();
        #pragma unroll
        for (int k = 0; k < 4; ++k) {
            bf16x8 aF = *(const bf16x8*)&AxS[(wm * 16 + (l & 15) + k) * 40 + (l >> 4) * 8];
            bf16x8 bF = *(const bf16x8*)&WbS[(k * 32 + wn * 16 + (l & 15)) * 40 + (l >> 4) * 8];
            acc = __builtin_amdgcn_mfma_f32_16x16x32_bf16(aF, bF, acc, 0, 0, 0);
        }
        __syncthreads();
    }
    int oc = o0 + wn * 16 + (l & 15);
    float bia = conv_b[oc];
    #pragma unroll
    for (int reg = 0; reg < 4; ++reg) {
        int m = wm * 16 + (l >> 4) * 4 + reg;
        float v = acc[reg] + bia;
        x_act[((size_t)(b * S + tl0 + m)) * DI + oc] = v / (1.0f + __expf(-v));
    }
}

// ---------------- ssm = x_act @ W_xp^T (33 outputs) ----------------
__global__ void ssm_k(const float* __restrict__ x_act, const float* __restrict__ W_xp,
                      float* __restrict__ dt_raw, float* __restrict__ Bm, float* __restrict__ Cm) {
    int row = blockIdx.x * 4 + (threadIdx.x >> 6);
    int lane = threadIdx.x & 63;
    const float* xr = x_act + (size_t)row * DI + lane * 8;
    float4 v0 = *(const float4*)xr;
    float4 v1 = *(const float4*)(xr + 4);
    for (int j = 0; j < 2 * N + 1; ++j) {
        const float* wr = W_xp + (size_t)j * DI + lane * 8;
        float4 w0 = *(const float4*)wr;
        float4 w1 = *(const float4*)(wr + 4);
        float acc = v0.x * w0.x + v0.y * w0.y + v0.z * w0.z + v0.w * w0.w
                  + v1.x * w1.x + v1.y * w1.y + v1.z * w1.z + v1.w * w1.w;
        for (int m = 1; m < 64; m <<= 1) acc += __shfl_xor(acc, m);
        if (lane == 0) {
            if (j == 0)           dt_raw[row] = acc;
            else if (j < 1 + N)   Bm[(size_t)row * N + (j - 1)] = acc;
            else                  Cm[(size_t)row * N + (j - 1 - N)] = acc;
        }
    }
}

// ---------------- rdeg = 1/max(sum_{s<t} adj,1); flag[t] ----------------
__global__ void deg_k(const float* __restrict__ adj, float* __restrict__ rdeg, int* __restrict__ flagI) {
    int t = blockIdx.x & (S - 1), b = blockIdx.x >> 9;
    int lane = threadIdx.x;
    const float* row = adj + ((size_t)(b * S + t)) * S;
    float s = 0.0f; bool anyp = false;
    for (int i = lane; i < t; i += 64) { float v = row[i]; s += v; anyp |= (v > 0.0f); }
    for (int m = 1; m < 64; m <<= 1) s += __shfl_xor(s, m);
    bool any = __any(anyp);
    if (lane == 0) {
        rdeg[b * S + t] = 1.0f / fmaxf(s, 1.0f);
        if (t > 0 && any) atomicOr(flagI + t, 1);
    }
}

// ---------------- E = exp(-softplus(dt)), zs = silu(z) ----------------
__global__ void ez_k(const float* __restrict__ dt_raw, const float* __restrict__ W_dt,
                     const float* __restrict__ b_dt, const float* __restrict__ xz,
                     float* __restrict__ E, float* __restrict__ zs) {
    int i = blockIdx.x * 256 + threadIdx.x;
    int d = i & (DI - 1);
    int row = i >> 9;
    float vv = dt_raw[row] * W_dt[d] + b_dt[d];
    E[i] = 1.0f / (1.0f + __expf(vv));
    float z = xz[(size_t)row * (2 * DI) + DI + d];
    zs[i] = z / (1.0f + __expf(-z));
}

// ================= fused chunk kernel (256-thread blocks, 192 blocks) =================
// histT: bf16 [b][dn][s]  (s contiguous -> MFMA B-operand friendly)
// Gold:  bf16 [parity][b][dn][j32]  = sum over ALL past chunks 0..c-2 for targets of chunk c
// Gnew:  bf16 [parity][b][dn][j32]  = previous chunk's contribution (from scan registers)
// blocks [0,64):   scan role (16 d-groups x 16 n), writes histT, Gnew(c+1), y
// blocks [64,192): gpast role: MFMA matmul Gold(c+1) = adj_rows x histT over chunks 0..c-1
__global__ __launch_bounds__(256) void chunk_k(const float* __restrict__ adj,
                                               const float* __restrict__ x_act,
                                               const float* __restrict__ E,
                                               const float* __restrict__ Bm,
                                               const float* __restrict__ Cm,
                                               const float* __restrict__ rdeg,
                                               const int* __restrict__ flagI,
                                               const float* __restrict__ Wr,
                                               const float* __restrict__ br,
                                               ushort16* __restrict__ Gold,
                                               ushort16* __restrict__ Gnew,
                                               ushort16* __restrict__ histT,
                                               float* __restrict__ hlast,
                                               const float* __restrict__ zs,
                                               ushort16* __restrict__ yzb, int c) {
    __shared__ __align__(16) char smemraw[16896];
    int tid = threadIdx.x;
    int cb = c * CHUNK;
    const size_t GBUF = (size_t)B * DN * 32;   // ushorts per parity

    if (blockIdx.x < 64) {
        // ---------------- scan role ----------------
        float* adjblk = (float*)smemraw;             // [32][33]
        float* adjN   = (float*)(smemraw + 4224);    // [32][33]
        float* eL     = (float*)(smemraw + 8448);    // [32][16]
        float* xaL    = (float*)(smemraw + 10496);   // [32][16]
        float* BnL    = (float*)(smemraw + 12544);   // [32][16]
        float* CnL    = (float*)(smemraw + 14592);   // [32][16]
        float* rdegL  = (float*)(smemraw + 16640);   // [32]
        int*   flL    = (int*)  (smemraw + 16768);   // [32]

        int b = blockIdx.x >> 5;
        int d0 = (blockIdx.x & 31) << 4;
        int n = tid & 15, grp = tid >> 4;            // grp 0..15
        int d = d0 + grp;
        int dn = d * N + n;

        // stage (coalesced, off the serial chain)
        {
            int j = tid >> 3;
            int s4 = (tid & 7) * 4;
            float4 av = *(const float4*)(adj + ((size_t)(b * S + cb + j)) * S + cb + s4);
            adjblk[j * 33 + s4 + 0] = av.x; adjblk[j * 33 + s4 + 1] = av.y;
            adjblk[j * 33 + s4 + 2] = av.z; adjblk[j * 33 + s4 + 3] = av.w;
            if (c < NCHUNK - 1) {
                float4 aw = *(const float4*)(adj + ((size_t)(b * S + cb + CHUNK + j)) * S + cb + s4);
                adjN[j * 33 + s4 + 0] = aw.x; adjN[j * 33 + s4 + 1] = aw.y;
                adjN[j * 33 + s4 + 2] = aw.z; adjN[j * 33 + s4 + 3] = aw.w;
            }
            int ds2 = (tid & 7) * 2;
            float2 ev = *(const float2*)(E     + ((size_t)(b * S + cb + j)) * DI + d0 + ds2);
            float2 xv = *(const float2*)(x_act + ((size_t)(b * S + cb + j)) * DI + d0 + ds2);
            eL [j * 16 + ds2] = ev.x; eL [j * 16 + ds2 + 1] = ev.y;
            xaL[j * 16 + ds2] = xv.x; xaL[j * 16 + ds2 + 1] = xv.y;
            float2 bv = *(const float2*)(Bm + ((size_t)(b * S + cb + j)) * N + ds2);
            float2 cv = *(const float2*)(Cm + ((size_t)(b * S + cb + j)) * N + ds2);
            BnL[j * 16 + ds2] = bv.x; BnL[j * 16 + ds2 + 1] = bv.y;
            CnL[j * 16 + ds2] = cv.x; CnL[j * 16 + ds2 + 1] = cv.y;
            if (tid < 32) {
                rdegL[tid] = rdeg[b * S + cb + tid];
                flL[tid]   = flagI[cb + tid];
            }
        }

        // presum Gold + Gnew into registers (coalesced 16B bursts)
        float gsum[CHUNK];
        #pragma unroll
        for (int j = 0; j < CHUNK; ++j) gsum[j] = 0.0f;
        if (c >= 1) {
            const ushort16* gn = Gnew + (size_t)(c & 1) * GBUF + ((size_t)b * DN + dn) * 32;
            #pragma unroll
            for (int qi = 0; qi < 4; ++qi) {
                uint4 q = *(const uint4*)(gn + qi * 8);
                gsum[qi * 8 + 0] += bflo(q.x); gsum[qi * 8 + 1] += bfhi(q.x);
                gsum[qi * 8 + 2] += bflo(q.y); gsum[qi * 8 + 3] += bfhi(q.y);
                gsum[qi * 8 + 4] += bflo(q.z); gsum[qi * 8 + 5] += bfhi(q.z);
                gsum[qi * 8 + 6] += bflo(q.w); gsum[qi * 8 + 7] += bfhi(q.w);
            }
        }
        if (c >= 2) {
            const ushort16* go = Gold + (size_t)(c & 1) * GBUF + ((size_t)b * DN + dn) * 32;
            #pragma unroll
            for (int qi = 0; qi < 4; ++qi) {
                uint4 q = *(const uint4*)(go + qi * 8);
                gsum[qi * 8 + 0] += bflo(q.x); gsum[qi * 8 + 1] += bfhi(q.x);
                gsum[qi * 8 + 2] += bflo(q.y); gsum[qi * 8 + 3] += bfhi(q.y);
                gsum[qi * 8 + 4] += bflo(q.z); gsum[qi * 8 + 5] += bfhi(q.z);
                gsum[qi * 8 + 6] += bflo(q.w); gsum[qi * 8 + 7] += bfhi(q.w);
            }
        }

        float wr[16];
        #pragma unroll
        for (int m = 0; m < 16; ++m) wr[m] = Wr[n * 16 + m];
        float brn = br[n];
        float h = (c == 0) ? 0.0f : hlast[b * DN + dn];
        __syncthreads();

        float hreg[CHUNK];
        #pragma unroll
        for (int j = 0; j < CHUNK; ++j) {
            float e  = eL [j * 16 + grp];
            float xa = xaL[j * 16 + grp];
            float Bn = BnL[j * 16 + n];
            h = h * e + xa * Bn;

            float g0 = gsum[j], g1 = 0.0f, g2 = 0.0f, g3 = 0.0f;
            const float* ar = adjblk + j * 33;
            #pragma unroll
            for (int sp = 0; sp < j; ++sp) {
                float a = ar[sp];                 // LDS broadcast
                if ((sp & 3) == 0) g0 += a * hreg[sp];
                else if ((sp & 3) == 1) g1 += a * hreg[sp];
                else if ((sp & 3) == 2) g2 += a * hreg[sp];
                else g3 += a * hreg[sp];
            }
            float g = ((g0 + g1) + (g2 + g3)) * rdegL[j];

            float a0 = brn, a1 = 0.0f, a2 = 0.0f, a3 = 0.0f;
            #pragma unroll
            for (int p = 0; p < 4; ++p) {
                a0 += __shfl(g, p * 4 + 0, 16) * wr[p * 4 + 0];
                a1 += __shfl(g, p * 4 + 1, 16) * wr[p * 4 + 1];
                a2 += __shfl(g, p * 4 + 2, 16) * wr[p * 4 + 2];
                a3 += __shfl(g, p * 4 + 3, 16) * wr[p * 4 + 3];
            }
            float acc = (a0 + a1) + (a2 + a3);
            if (flL[j]) h += 0.1f * acc / (1.0f + __expf(-acc));
            hreg[j] = h;
        }
        hlast[b * DN + dn] = h;

        // tail: histT (transposed, s-contiguous), y outputs, Gnew(c+1)
        {
            ushort16* ht = histT + ((size_t)b * DN + dn) * S + cb;
            #pragma unroll
            for (int qi = 0; qi < 4; ++qi) {
                uint4 q;
                q.x = pk2(hreg[qi * 8 + 0], hreg[qi * 8 + 1]);
                q.y = pk2(hreg[qi * 8 + 2], hreg[qi * 8 + 3]);
                q.z = pk2(hreg[qi * 8 + 4], hreg[qi * 8 + 5]);
                q.w = pk2(hreg[qi * 8 + 6], hreg[qi * 8 + 7]);
                *(uint4*)(ht + qi * 8) = q;
            }
        }
        size_t baseTD = ((size_t)(b * S + cb)) * DI + d;
        #pragma unroll
        for (int j = 0; j < CHUNK; ++j) {
            float rs = hreg[j] * CnL[j * 16 + n];
            rs += __shfl_xor(rs, 1);
            rs += __shfl_xor(rs, 2);
            rs += __shfl_xor(rs, 4);
            rs += __shfl_xor(rs, 8);
            if (n == 0) {
                float zv = zs[baseTD + (size_t)j * DI];
                yzb[baseTD + (size_t)j * DI] = f2bf(rs * zv);
            }
        }
        if (c < NCHUNK - 1) {
            float gn[CHUNK];
            #pragma unroll
            for (int jj = 0; jj < CHUNK; ++jj) {
                float a0 = 0.0f, a1 = 0.0f;
                const float* arN = adjN + jj * 33;
                #pragma unroll
                for (int sp = 0; sp < CHUNK; sp += 2) {
                    a0 += arN[sp]     * hreg[sp];
                    a1 += arN[sp + 1] * hreg[sp + 1];
                }
                gn[jj] = a0 + a1;
            }
            ushort16* gw = Gnew + (size_t)((c + 1) & 1) * GBUF + ((size_t)b * DN + dn) * 32;
            #pragma unroll
            for (int qi = 0; qi < 4; ++qi) {
                uint4 q;
                q.x = pk2(gn[qi * 8 + 0], gn[qi * 8 + 1]);
                q.y = pk2(gn[qi * 8 + 2], gn[qi * 8 + 3]);
                q.z = pk2(gn[qi * 8 + 4], gn[qi * 8 + 5]);
                q.w = pk2(gn[qi * 8 + 6], gn[qi * 8 + 7]);
                *(uint4*)(gw + qi * 8) = q;
            }
        }
    } else {
        // ---------------- gpast role: Gold(c+1) via bf16 MFMA ----------------
        if (c == 0 || c >= NCHUNK - 1) return;
        short* As = (short*)smemraw;            // [32][40]
        short* Ws = (short*)(smemraw + 2560);   // [128][40]
        int idx = blockIdx.x - 64;              // 0..127
        int b = idx >> 6;
        int dn0 = (idx & 63) * 128;
        int l = tid & 63, wid = tid >> 6;
        int wjm = wid & 1;                      // j half (16)
        int wn2 = wid >> 1;                     // dn half (64 within 128)

        f32x4 acc[4] = {};
        for (int ks = 0; ks < c; ++ks) {
            {
                int j = tid >> 3, s4 = (tid & 7) * 4;
                float4 av = *(const float4*)(adj + ((size_t)(b * S + cb + CHUNK + j)) * S + ks * CHUNK + s4);
                As[j * 40 + s4 + 0] = (short)f2bf(av.x);
                As[j * 40 + s4 + 1] = (short)f2bf(av.y);
                As[j * 40 + s4 + 2] = (short)f2bf(av.z);
                As[j * 40 + s4 + 3] = (short)f2bf(av.w);
                #pragma unroll
                for (int q = 0; q < 2; ++q) {
                    int e = q * 256 + tid;
                    int r = e >> 2, seg = e & 3;
                    *(uint4*)&Ws[r * 40 + seg * 8] =
                        *(const uint4*)(histT + ((size_t)b * DN + dn0 + r) * S + ks * CHUNK + seg * 8);
                }
            }
            __syncthreads();
            bf16x8 aF = *(const bf16x8*)&As[(wjm * 16 + (l & 15)) * 40 + (l >> 4) * 8];
            #pragma unroll
            for (int bn = 0; bn < 4; ++bn) {
                bf16x8 bF = *(const bf16x8*)&Ws[(wn2 * 64 + bn * 16 + (l & 15)) * 40 + (l >> 4) * 8];
                acc[bn] = __builtin_amdgcn_mfma_f32_16x16x32_bf16(aF, bF, acc[bn], 0, 0, 0);
            }
            __syncthreads();
        }
        int jb = wjm * 16 + (l >> 4) * 4;
        ushort16* gbase = Gold + (size_t)((c + 1) & 1) * GBUF;
        #pragma unroll
        for (int bn = 0; bn < 4; ++bn) {
            int dnc = dn0 + wn2 * 64 + bn * 16 + (l & 15);
            uint2 o;
            o.x = pk2(acc[bn][0], acc[bn][1]);
            o.y = pk2(acc[bn][2], acc[bn][3]);
            *(uint2*)(gbase + ((size_t)b * DN + dnc) * 32 + jb) = o;
        }
    }
}

// ---------------- launch ----------------
extern "C" void kernel_launch(void* const* d_in, const int* in_sizes, int n_in,
                              void* d_out, int out_size, void* d_ws, size_t ws_size,
                              hipStream_t stream) {
    const float* x      = (const float*)d_in[0];
    const float* adj    = (const float*)d_in[1];
    const float* ln_w   = (const float*)d_in[2];
    const float* ln_b   = (const float*)d_in[3];
    const float* W_in   = (const float*)d_in[4];
    const float* conv_w = (const float*)d_in[5];
    const float* conv_b = (const float*)d_in[6];
    const float* W_xp   = (const float*)d_in[7];
    const float* W_dt   = (const float*)d_in[8];
    const float* b_dt   = (const float*)d_in[9];
    const float* Wr     = (const float*)d_in[10];
    const float* br     = (const float*)d_in[11];
    const float* W_out  = (const float*)d_in[12];
    float* out = (float*)d_out;

    float* ws = (float*)d_ws;
    size_t off = 0;
    float* xz     = ws + off; off += (size_t)B * S * 2 * DI;
    float* x_act  = ws + off; off += (size_t)B * S * DI;
    float* dt_raw = ws + off; off += (size_t)B * S;
    float* Bmb    = ws + off; off += (size_t)B * S * N;
    float* Cmb    = ws + off; off += (size_t)B * S * N;
    float* rdegp  = ws + off; off += (size_t)B * S;
    int*   flagI  = (int*)(ws + off); off += S;
    float* Ebuf   = ws + off; off += (size_t)B * S * DI;
    float* zsbuf  = ws + off; off += (size_t)B * S * DI;
    float* hlast  = ws + off; off += (size_t)B * DN;
    ushort16* xnb    = (ushort16*)(ws + off); off += (size_t)B * S * D / 2;
    ushort16* yzb    = (ushort16*)(ws + off); off += (size_t)B * S * DI / 2;
    ushort16* histT  = (ushort16*)(ws + off); off += (size_t)B * DN * S / 2;
    ushort16* Gold   = (ushort16*)(ws + off); off += (size_t)2 * B * DN * 32 / 2;
    ushort16* Gnew   = (ushort16*)(ws + off); off += (size_t)2 * B * DN * 32 / 2;
    ushort16* xpb    = (ushort16*)(ws + off); off += (size_t)B * (S + 3) * DI / 2;
    ushort16* W_inb  = (ushort16*)(ws + off); off += (size_t)2 * DI * D / 2;
    ushort16* W_outb = (ushort16*)(ws + off); off += (size_t)D * DI / 2;

    hipMemsetAsync(flagI, 0, S * sizeof(int), stream);
    hipMemsetAsync(xpb, 0, (size_t)B * (S + 3) * DI * 2, stream);

    ln_k<<<B * S, 64, 0, stream>>>(x, ln_w, ln_b, xnb);
    wcast_k<<<(2 * DI * D) / 1024, 256, 0, stream>>>(W_in, W_inb);
    wcast_k<<<(D * DI) / 1024, 256, 0, stream>>>(W_out, W_outb);
    gemmb_k<<<dim3(2 * DI / 64, B * S / 64), 256, 0, stream>>>(xnb, W_inb, nullptr, xz, B * S, 2 * DI, D);
    cast_k<<<B * S * DI / (256 * 8), 256, 0, stream>>>(xz, xpb);
    convm_k<<<dim3(DI / 32, B * S / 32), 256, 0, stream>>>(xpb, conv_w, conv_b, x_act);
    ssm_k<<<B * S / 4, 256, 0, stream>>>(x_act, W_xp, dt_raw, Bmb, Cmb);
    deg_k<<<B * S, 64, 0, stream>>>(adj, rdegp, flagI);
    ez_k<<<B * S * DI / 256, 256, 0, stream>>>(dt_raw, W_dt, b_dt, xz, Ebuf, zsbuf);

    for (int c = 0; c < NCHUNK; ++c)
        chunk_k<<<192, 256, 0, stream>>>(adj, x_act, Ebuf, Bmb, Cmb, rdegp, flagI,
                                         Wr, br, Gold, Gnew, histT, hlast, zsbuf, yzb, c);

    gemmb_k<<<dim3(D / 64, B * S / 64), 256, 0, stream>>>(yzb, W_outb, x, out, B * S, D, DI);
}